// Round 13
// baseline (179.283 us; speedup 1.0000x reference)
//
#include <hip/hip_runtime.h>

#define NPOS 576      // B*oH*oW
#define KTOT 144      // KH*KW*IC
#define NOC 32
#define NP 16
#define OCP 512       // columns per position (32 oc x 16 p)
#define NCQ 128       // column-quads per row (OCP/4)
#define NSLOT 8       // row-slots (threads 1024 = 128 quads x 8 slots)
#define RPT 18        // rows per thread (KTOT/NSLOT)
#define EPSF 1e-7f
#define LOG2PIF 1.83787706640934548356f

// Register-resident-V EM routing (f32 in/out):
//  - 1024 threads/block; thread owns column-quad c and row-slot rs
//  - V loaded ONCE into vloc[18] (72 VGPR); transitions are pure VALU+LDS
//  - logits for all 144 rows in one phase; softmax one 4608-item sweep
//  - ~13 barriers total (vs ~26 in round 12)
__global__ __launch_bounds__(1024) void em_routing(
    const float* __restrict__ Vf, const float* __restrict__ Af,
    const float* __restrict__ Bup, const float* __restrict__ Bap,
    float* __restrict__ out)
{
  const int pos = blockIdx.x;           // 0..575
  const int t   = (int)threadIdx.x;     // 0..1023
  const int c   = t & 127;              // column-quad: columns 4c..4c+3
  const int rs  = t >> 7;               // row-slot 0..7
  const int oc  = c >> 2;

  __shared__ float sA[KTOT];
  __shared__ float sL[KTOT][NOC];       // logits -> weights (18 KB)
  __shared__ float sRed[NSLOT][NCQ][9]; // cross-slot moment reduce (36 KB)
  __shared__ float sX[NOC];
  __shared__ float sBase[NOC];

  const float4* __restrict__ V4 =
      (const float4*)(Vf + (size_t)pos * (KTOT * OCP));

  if (t < KTOT) sA[t] = Af[pos * KTOT + t];
  const float Bu = Bup[oc];
  const float Ba = Bap[oc];
  __syncthreads();

  // ---- single V pass: load to registers + pass-0 moments (w = a[k]/32) ----
  float4 vloc[RPT];
  float  s0 = 0.f;
  float4 s1 = {0.f,0.f,0.f,0.f}, s2 = {0.f,0.f,0.f,0.f};
  #pragma unroll
  for (int r = 0; r < RPT; ++r) {
    const int k = rs + NSLOT * r;
    vloc[r] = V4[k * NCQ + c];
    const float w = sA[k] * (1.0f / 32.0f);
    const float4 v = vloc[r];
    s0 += w;
    s1.x += w * v.x; s1.y += w * v.y; s1.z += w * v.z; s1.w += w * v.w;
    s2.x += w * v.x * v.x; s2.y += w * v.y * v.y;
    s2.z += w * v.z * v.z; s2.w += w * v.w * v.w;
  }

  float4 mu, sig;
  float aout = 0.5f;

  for (int it = 0; it < 3; ++it) {
    const float lam = (it == 0) ? 5e-4f : (it == 1) ? 9.75e-4f : 1.42625e-3f;

    // ---- cross-row-slot reduction of {s0, s1, s2} (9 floats) ----
    sRed[rs][c][0] = s0;
    sRed[rs][c][1] = s1.x; sRed[rs][c][2] = s1.y;
    sRed[rs][c][3] = s1.z; sRed[rs][c][4] = s1.w;
    sRed[rs][c][5] = s2.x; sRed[rs][c][6] = s2.y;
    sRed[rs][c][7] = s2.z; sRed[rs][c][8] = s2.w;
    __syncthreads();                       // B-red
    {
      float a0=0.f,a1=0.f,a2=0.f,a3=0.f,a4=0.f,a5=0.f,a6=0.f,a7=0.f,a8=0.f;
      #pragma unroll
      for (int q = 0; q < NSLOT; ++q) {
        a0 += sRed[q][c][0];
        a1 += sRed[q][c][1]; a2 += sRed[q][c][2];
        a3 += sRed[q][c][3]; a4 += sRed[q][c][4];
        a5 += sRed[q][c][5]; a6 += sRed[q][c][6];
        a7 += sRed[q][c][7]; a8 += sRed[q][c][8];
      }
      s0 = a0;
      s1.x = a1; s1.y = a2; s1.z = a3; s1.w = a4;
      s2.x = a5; s2.y = a6; s2.z = a7; s2.w = a8;
    }

    const float inv = 1.0f / (s0 + EPSF);
    mu.x = s1.x * inv; mu.y = s1.y * inv; mu.z = s1.z * inv; mu.w = s1.w * inv;
    sig.x = fmaxf(s2.x * inv - mu.x * mu.x, 1e-30f);
    sig.y = fmaxf(s2.y * inv - mu.y * mu.y, 1e-30f);
    sig.z = fmaxf(s2.z * inv - mu.z * mu.z, 1e-30f);
    sig.w = fmaxf(s2.w * inv - mu.w * mu.w, 1e-30f);

    // L = sum over 16 p of log(sigma): own 4 + width-4 butterfly
    float Lown = logf(sig.x) + logf(sig.y) + logf(sig.z) + logf(sig.w);
    float L1 = Lown + __shfl_xor(Lown, 1, 4);
    const float L = L1 + __shfl_xor(L1, 2, 4);

    const float x = lam * (Ba - s0 * (16.0f * Bu + 0.5f * L));
    if (rs == 0 && (c & 3) == 0) sX[oc] = x;
    __syncthreads();                       // B-x
    float ss = 0.f;
    #pragma unroll
    for (int j = 0; j < NOC; ++j) ss += sX[j] * sX[j];
    const float nrm = fmaxf(sqrtf(ss), 1e-12f);
    aout = 1.0f / (1.0f + expf(-x / nrm));

    if (it == 2) break;                    // final E-step dead in reference

    float4 c0q;
    c0q.x = 1.0f / (2.0f * sig.x + EPSF);
    c0q.y = 1.0f / (2.0f * sig.y + EPSF);
    c0q.z = 1.0f / (2.0f * sig.z + EPSF);
    c0q.w = 1.0f / (2.0f * sig.w + EPSF);
    if (rs == 0 && (c & 3) == 0)
      sBase[oc] = logf(aout) + (-0.5f * (16.0f * LOG2PIF + L) + EPSF);
    __syncthreads();                       // B-base

    // ---- logits for ALL 144 rows (from registers) ----
    #pragma unroll
    for (int r = 0; r < RPT; ++r) {
      const float4 v = vloc[r];
      const float dx = v.x - mu.x, dy = v.y - mu.y,
                  dz = v.z - mu.z, dw = v.w - mu.w;
      float q = dx * dx * c0q.x + dy * dy * c0q.y
              + dz * dz * c0q.z + dw * dw * c0q.w;
      q += __shfl_xor(q, 1, 4);
      q += __shfl_xor(q, 2, 4);
      if ((c & 3) == 0) sL[rs + NSLOT * r][oc] = q;
    }
    __syncthreads();                       // B-logit

    // ---- softmax over oc per row (4608 items), fold a[k] ----
    #pragma unroll
    for (int j = 0; j < 5; ++j) {
      const int idx = t + 1024 * j;
      if (idx < KTOT * NOC) {
        const int kl = idx >> 5, o = idx & 31;
        const float val = sBase[o] - sL[kl][o];
        float mx = val;
        #pragma unroll
        for (int m = 1; m < 32; m <<= 1) mx = fmaxf(mx, __shfl_xor(mx, m, 32));
        const float e = expf(val - mx);
        float sum = e;
        #pragma unroll
        for (int m = 1; m < 32; m <<= 1) sum += __shfl_xor(sum, m, 32);
        sL[kl][o] = e * (sA[kl] / sum);
      }
    }
    __syncthreads();                       // B-weights

    // ---- next-iteration moments from registers ----
    s0 = 0.f;
    s1.x = s1.y = s1.z = s1.w = 0.f;
    s2.x = s2.y = s2.z = s2.w = 0.f;
    #pragma unroll
    for (int r = 0; r < RPT; ++r) {
      const float w = sL[rs + NSLOT * r][oc];
      const float4 v = vloc[r];
      s0 += w;
      s1.x += w * v.x; s1.y += w * v.y; s1.z += w * v.z; s1.w += w * v.w;
      s2.x += w * v.x * v.x; s2.y += w * v.y * v.y;
      s2.z += w * v.z * v.z; s2.w += w * v.w * v.w;
    }
  }

  // ---- outputs (f32): mu [0:294912] | a_out [294912:313344] | sigma [...] ----
  if (rs == 0) {
    float4* __restrict__ out4 = (float4*)out;
    out4[(size_t)pos * NCQ + c]          = mu;   // mu block
    out4[78336u + (size_t)pos * NCQ + c] = sig;  // sigma block (313344/4)
    if ((c & 3) == 0) out[294912u + (size_t)pos * NOC + oc] = aout;
  }
}

extern "C" void kernel_launch(void* const* d_in, const int* in_sizes, int n_in,
                              void* d_out, int out_size, void* d_ws, size_t ws_size,
                              hipStream_t stream) {
  em_routing<<<NPOS, 1024, 0, stream>>>((const float*)d_in[0], (const float*)d_in[1],
                                        (const float*)d_in[2], (const float*)d_in[3],
                                        (float*)d_out);
}

// Round 14
// 175.763 us; speedup vs baseline: 1.0200x; 1.0200x over previous
//
#include <hip/hip_runtime.h>

#define NPOS 576      // B*oH*oW
#define KTOT 144      // KH*KW*IC
#define NOC 32
#define NP 16
#define OCP 512       // columns per position (32 oc x 16 p)
#define NCQ 128       // column-quads per row (OCP/4)
#define NSLOT 8       // row-slots (threads 1024 = 128 quads x 8 slots)
#define RPT 18        // rows per thread (KTOT/NSLOT)
#define EPSF 1e-7f
#define LOG2PIF 1.83787706640934548356f

// Register-resident-V EM routing (f32 in/out).
// Round 14 fix: __launch_bounds__(1024, 4) -> 4 waves/EU -> 1 block/CU ->
// 128-VGPR budget, so vloc[18] (72 VGPR) stays in registers (round 13's
// plain (1024) bound made the compiler target 64 VGPR and spill vloc to
// scratch: VGPR_Count=64 + WRITE_SIZE 185MB were the tells).
__global__ __launch_bounds__(1024, 4) void em_routing(
    const float* __restrict__ Vf, const float* __restrict__ Af,
    const float* __restrict__ Bup, const float* __restrict__ Bap,
    float* __restrict__ out)
{
  const int pos = blockIdx.x;           // 0..575
  const int t   = (int)threadIdx.x;     // 0..1023
  const int c   = t & 127;              // column-quad: columns 4c..4c+3
  const int rs  = t >> 7;               // row-slot 0..7
  const int oc  = c >> 2;

  __shared__ float sA[KTOT];
  __shared__ float sL[KTOT][NOC];       // logits -> weights (18 KB)
  __shared__ float sRed[NSLOT][NCQ][9]; // cross-slot moment reduce (36 KB)
  __shared__ float sX[NOC];
  __shared__ float sBase[NOC];

  const float4* __restrict__ V4 =
      (const float4*)(Vf + (size_t)pos * (KTOT * OCP));

  if (t < KTOT) sA[t] = Af[pos * KTOT + t];
  const float Bu = Bup[oc];
  const float Ba = Bap[oc];
  __syncthreads();

  // ---- single V pass: load to registers + pass-0 moments (w = a[k]/32) ----
  float4 vloc[RPT];
  float  s0 = 0.f;
  float4 s1 = {0.f,0.f,0.f,0.f}, s2 = {0.f,0.f,0.f,0.f};
  #pragma unroll
  for (int r = 0; r < RPT; ++r) {
    const int k = rs + NSLOT * r;
    vloc[r] = V4[k * NCQ + c];
    const float w = sA[k] * (1.0f / 32.0f);
    const float4 v = vloc[r];
    s0 += w;
    s1.x += w * v.x; s1.y += w * v.y; s1.z += w * v.z; s1.w += w * v.w;
    s2.x += w * v.x * v.x; s2.y += w * v.y * v.y;
    s2.z += w * v.z * v.z; s2.w += w * v.w * v.w;
  }

  float4 mu, sig;
  float aout = 0.5f;

  for (int it = 0; it < 3; ++it) {
    const float lam = (it == 0) ? 5e-4f : (it == 1) ? 9.75e-4f : 1.42625e-3f;

    // ---- cross-row-slot reduction of {s0, s1, s2} (9 floats) ----
    sRed[rs][c][0] = s0;
    sRed[rs][c][1] = s1.x; sRed[rs][c][2] = s1.y;
    sRed[rs][c][3] = s1.z; sRed[rs][c][4] = s1.w;
    sRed[rs][c][5] = s2.x; sRed[rs][c][6] = s2.y;
    sRed[rs][c][7] = s2.z; sRed[rs][c][8] = s2.w;
    __syncthreads();                       // B-red
    {
      float a0=0.f,a1=0.f,a2=0.f,a3=0.f,a4=0.f,a5=0.f,a6=0.f,a7=0.f,a8=0.f;
      #pragma unroll
      for (int q = 0; q < NSLOT; ++q) {
        a0 += sRed[q][c][0];
        a1 += sRed[q][c][1]; a2 += sRed[q][c][2];
        a3 += sRed[q][c][3]; a4 += sRed[q][c][4];
        a5 += sRed[q][c][5]; a6 += sRed[q][c][6];
        a7 += sRed[q][c][7]; a8 += sRed[q][c][8];
      }
      s0 = a0;
      s1.x = a1; s1.y = a2; s1.z = a3; s1.w = a4;
      s2.x = a5; s2.y = a6; s2.z = a7; s2.w = a8;
    }

    const float inv = 1.0f / (s0 + EPSF);
    mu.x = s1.x * inv; mu.y = s1.y * inv; mu.z = s1.z * inv; mu.w = s1.w * inv;
    sig.x = fmaxf(s2.x * inv - mu.x * mu.x, 1e-30f);
    sig.y = fmaxf(s2.y * inv - mu.y * mu.y, 1e-30f);
    sig.z = fmaxf(s2.z * inv - mu.z * mu.z, 1e-30f);
    sig.w = fmaxf(s2.w * inv - mu.w * mu.w, 1e-30f);

    // L = sum over 16 p of log(sigma): own 4 + width-4 butterfly
    float Lown = logf(sig.x) + logf(sig.y) + logf(sig.z) + logf(sig.w);
    float L1 = Lown + __shfl_xor(Lown, 1, 4);
    const float L = L1 + __shfl_xor(L1, 2, 4);

    const float x = lam * (Ba - s0 * (16.0f * Bu + 0.5f * L));
    if (rs == 0 && (c & 3) == 0) sX[oc] = x;
    __syncthreads();                       // B-x
    float ss = 0.f;
    #pragma unroll
    for (int j = 0; j < NOC; ++j) ss += sX[j] * sX[j];
    const float nrm = fmaxf(sqrtf(ss), 1e-12f);
    aout = 1.0f / (1.0f + expf(-x / nrm));

    if (it == 2) break;                    // final E-step dead in reference

    float4 c0q;
    c0q.x = 1.0f / (2.0f * sig.x + EPSF);
    c0q.y = 1.0f / (2.0f * sig.y + EPSF);
    c0q.z = 1.0f / (2.0f * sig.z + EPSF);
    c0q.w = 1.0f / (2.0f * sig.w + EPSF);
    if (rs == 0 && (c & 3) == 0)
      sBase[oc] = logf(aout) + (-0.5f * (16.0f * LOG2PIF + L) + EPSF);
    __syncthreads();                       // B-base

    // ---- logits for ALL 144 rows (from registers) ----
    #pragma unroll
    for (int r = 0; r < RPT; ++r) {
      const float4 v = vloc[r];
      const float dx = v.x - mu.x, dy = v.y - mu.y,
                  dz = v.z - mu.z, dw = v.w - mu.w;
      float q = dx * dx * c0q.x + dy * dy * c0q.y
              + dz * dz * c0q.z + dw * dw * c0q.w;
      q += __shfl_xor(q, 1, 4);
      q += __shfl_xor(q, 2, 4);
      if ((c & 3) == 0) sL[rs + NSLOT * r][oc] = q;
    }
    __syncthreads();                       // B-logit

    // ---- softmax over oc per row (4608 items), fold a[k] ----
    #pragma unroll
    for (int j = 0; j < 5; ++j) {
      const int idx = t + 1024 * j;
      if (idx < KTOT * NOC) {
        const int kl = idx >> 5, o = idx & 31;
        const float val = sBase[o] - sL[kl][o];
        float mx = val;
        #pragma unroll
        for (int m = 1; m < 32; m <<= 1) mx = fmaxf(mx, __shfl_xor(mx, m, 32));
        const float e = expf(val - mx);
        float sum = e;
        #pragma unroll
        for (int m = 1; m < 32; m <<= 1) sum += __shfl_xor(sum, m, 32);
        sL[kl][o] = e * (sA[kl] / sum);
      }
    }
    __syncthreads();                       // B-weights

    // ---- next-iteration moments from registers ----
    s0 = 0.f;
    s1.x = s1.y = s1.z = s1.w = 0.f;
    s2.x = s2.y = s2.z = s2.w = 0.f;
    #pragma unroll
    for (int r = 0; r < RPT; ++r) {
      const float w = sL[rs + NSLOT * r][oc];
      const float4 v = vloc[r];
      s0 += w;
      s1.x += w * v.x; s1.y += w * v.y; s1.z += w * v.z; s1.w += w * v.w;
      s2.x += w * v.x * v.x; s2.y += w * v.y * v.y;
      s2.z += w * v.z * v.z; s2.w += w * v.w * v.w;
    }
  }

  // ---- outputs (f32): mu [0:294912] | a_out [294912:313344] | sigma [...] ----
  if (rs == 0) {
    float4* __restrict__ out4 = (float4*)out;
    out4[(size_t)pos * NCQ + c]          = mu;   // mu block
    out4[78336u + (size_t)pos * NCQ + c] = sig;  // sigma block (313344/4)
    if ((c & 3) == 0) out[294912u + (size_t)pos * NOC + oc] = aout;
  }
}

extern "C" void kernel_launch(void* const* d_in, const int* in_sizes, int n_in,
                              void* d_out, int out_size, void* d_ws, size_t ws_size,
                              hipStream_t stream) {
  em_routing<<<NPOS, 1024, 0, stream>>>((const float*)d_in[0], (const float*)d_in[1],
                                        (const float*)d_in[2], (const float*)d_in[3],
                                        (float*)d_out);
}